// Round 18
// baseline (384.388 us; speedup 1.0000x reference)
//
#include <hip/hip_runtime.h>
#include <math.h>

#define F 64
#define LDIM 16
#define NRAD 8
#define HID_R 64
#define HID_READ 32
#define NSPEC 10

typedef __attribute__((ext_vector_type(8))) short short8v;
typedef __attribute__((ext_vector_type(4))) float f32x4;

__device__ __forceinline__ int l_of_m(int m) {
    return (m == 0) ? 0 : (m < 4) ? 1 : (m < 9) ? 2 : 3;
}
__device__ __forceinline__ float silu(float x) { return x / (1.0f + __expf(-x)); }
__device__ __forceinline__ unsigned short bf16bits(float x) {
    unsigned int u = __float_as_uint(x);
    u += 0x7fffu + ((u >> 16) & 1u);   // RNE
    return (unsigned short)(u >> 16);
}
__device__ __forceinline__ float bf16tof(unsigned short b) {
    return __uint_as_float(((unsigned int)b) << 16);
}
// Bit-exact lane broadcast on the VALU pipe (v_readlane_b32), NOT the DS pipe.
// BITCAST through uint — a float arg would be float->uint CONVERTED (r6/7 bug).
__device__ __forceinline__ float lanebcast(float v, int l) {
    return __uint_as_float(__builtin_amdgcn_readlane(__float_as_uint(v), l));
}

__device__ __forceinline__ void geo_core(const float* __restrict__ vectors, int e,
                                         float* Ye_out, float* remb_out) {
    float vx = vectors[e * 3 + 0];
    float vy = vectors[e * 3 + 1];
    float vz = vectors[e * 3 + 2];
    float r = sqrtf(vx * vx + vy * vy + vz * vz + 1e-12f);
    float x = vx / r, y = vy / r, z = vz / r;
    float r2 = x * x + y * y + z * z;
    Ye_out[0]  = 1.0f;  Ye_out[1] = x;  Ye_out[2] = y;  Ye_out[3] = z;
    Ye_out[4]  = x * y; Ye_out[5] = y * z; Ye_out[6] = 3.0f * z * z - r2; Ye_out[7] = x * z;
    Ye_out[8]  = x * x - y * y;
    Ye_out[9]  = y * (3.0f * x * x - y * y);
    Ye_out[10] = x * y * z;
    Ye_out[11] = y * (5.0f * z * z - r2);
    Ye_out[12] = z * (5.0f * z * z - 3.0f * r2);
    Ye_out[13] = x * (5.0f * z * z - r2);
    Ye_out[14] = z * (x * x - y * y);
    Ye_out[15] = x * (x * x - 3.0f * y * y);
    float u = r / 5.0f;
    float env = (u < 1.0f) ? (1.0f - u) * (1.0f - u) * (1.0f + 2.0f * u) : 0.0f;
    float inv = env / (u + 1e-6f);
    const float PI = 3.14159265358979323846f;
#pragma unroll
    for (int k = 1; k <= NRAD; k++) remb_out[k - 1] = sinf(PI * (float)k * u) * inv;
}

__device__ __forceinline__ void hid_write(const float* remb, const float* w1,
                                          unsigned short* __restrict__ Hb, int e) {
    float h[HID_R];
#pragma unroll
    for (int j = 0; j < HID_R; j++) {
        float a = 0.0f;
#pragma unroll
        for (int k = 0; k < NRAD; k++) a += remb[k] * w1[k * HID_R + j];
        h[j] = silu(a);
    }
    unsigned int* dst = (unsigned int*)(Hb + (size_t)e * HID_R);
#pragma unroll
    for (int w = 0; w < 32; w++) {
        unsigned int lo = bf16bits(h[2 * w]);
        unsigned int hi = bf16bits(h[2 * w + 1]);
        dst[w] = lo | (hi << 16);
    }
}

// =========== K1: geo + hist + BOTH H layers  |  conv_w2 (2 tail blocks) ===========
__global__ void k1_kernel(const float* __restrict__ vectors,
                          const float* __restrict__ w_r1,   // (2,8,64)
                          const float* __restrict__ w_r2,   // (2,64,512)
                          const int* __restrict__ receivers,
                          float* __restrict__ Y,
                          unsigned short* __restrict__ Hb0,
                          unsigned short* __restrict__ Hb1,
                          int* __restrict__ cnt,
                          unsigned short* __restrict__ w2f,
                          int E, int ngeo) {
    const int bid = blockIdx.x;
    if (bid >= ngeo) {
        const int layer = bid - ngeo;
        const float* src = w_r2 + (size_t)layer * HID_R * 512;
        unsigned short* dst = w2f + (size_t)layer * 32768;
        for (int idx = threadIdx.x; idx < 32768; idx += 256) {
            int j    = idx & 7;
            int lane = (idx >> 3) & 63;
            int ks   = (idx >> 9) & 1;
            int ct   = idx >> 10;
            int k    = ks * 32 + (lane >> 4) * 8 + j;
            int col  = ct * 16 + (lane & 15);
            dst[idx] = bf16bits(src[k * 512 + col]);
        }
        return;
    }
    const int e = bid * 256 + threadIdx.x;
    if (e >= E) return;
    atomicAdd(&cnt[receivers[e]], 1);
    float ye[16], remb[NRAD];
    geo_core(vectors, e, ye, remb);
    float4* Yd = (float4*)(Y + (size_t)e * 16);
    Yd[0] = make_float4(ye[0], ye[1], ye[2], ye[3]);
    Yd[1] = make_float4(ye[4], ye[5], ye[6], ye[7]);
    Yd[2] = make_float4(ye[8], ye[9], ye[10], ye[11]);
    Yd[3] = make_float4(ye[12], ye[13], ye[14], ye[15]);
    hid_write(remb, w_r1, Hb0, e);
    hid_write(remb, w_r1 + NRAD * HID_R, Hb1, e);
}

// ---------- fallback geo ----------
__global__ void geo_kernel(const float* __restrict__ vectors,
                           float* __restrict__ Y, float* __restrict__ Remb, int E) {
    int e = blockIdx.x * 256 + threadIdx.x;
    if (e >= E) return;
    float ye[16], remb[NRAD];
    geo_core(vectors, e, ye, remb);
#pragma unroll
    for (int m = 0; m < 16; m++) Y[(size_t)e * 16 + m] = ye[m];
#pragma unroll
    for (int k = 0; k < NRAD; k++) Remb[(size_t)e * NRAD + k] = remb[k];
}

// ---------- CSR scan (1024 threads) / scatter ----------
__global__ void scan_kernel(const int* __restrict__ cnt, int* __restrict__ offs, int N) {
    __shared__ int buf[1024];
    __shared__ int carry;
    int t = threadIdx.x;
    if (t == 0) carry = 0;
    __syncthreads();
    for (int base = 0; base < N; base += 1024) {
        int v = (base + t < N) ? cnt[base + t] : 0;
        buf[t] = v;
        __syncthreads();
#pragma unroll
        for (int off = 1; off < 1024; off <<= 1) {
            int x = (t >= off) ? buf[t - off] : 0;
            __syncthreads();
            buf[t] += x;
            __syncthreads();
        }
        if (base + t < N) offs[base + t] = carry + buf[t] - v;   // exclusive
        __syncthreads();
        if (t == 0) carry += buf[1023];
        __syncthreads();
    }
    if (t == 0) offs[N] = carry;
}

__global__ void scatter_kernel(const int* __restrict__ receivers,
                               const int* __restrict__ senders,
                               const int* __restrict__ offs, int* __restrict__ cur,
                               int* __restrict__ eidx, int* __restrict__ snd_csr,
                               int* __restrict__ rcv_csr, int E) {
    int e = blockIdx.x * 256 + threadIdx.x;
    if (e >= E) return;
    int r = receivers[e];
    int pos = atomicAdd(&cur[r], 1);
    int t = offs[r] + pos;
    eidx[t] = e;
    snd_csr[t] = senders[e];
    rcv_csr[t] = r;
}

// ---------- feats init (fallback only, fp32) ----------
__global__ void init_feats_kernel(const float* __restrict__ w_embed,
                                  const int* __restrict__ specie,
                                  float* __restrict__ feats_t, int N) {
    int n = blockIdx.x;
    int sp = specie[n];
    for (int i = threadIdx.x; i < F * LDIM; i += 256) {
        int m = i >> 6;
        int f = i & 63;
        feats_t[(size_t)n * (F * LDIM) + i] = (m == 0) ? w_embed[sp * F + f] : 0.0f;
    }
}

// ========== fused edge+node kernel v10: edges AND node math in one kernel ==========
// r15's proven edge structure (fp32 R 532/66 LDS, linear [n][m][f] bf16 feats,
// depth-1 prefetch, all 4 waves per edge). NEW: block owns nodes {n0,n0+1}
// completely -> accumulate into named register sets accA/accB (uniform branch,
// no runtime indexing) and run the node-level math IN-KERNEL:
//   L0 epilogue: node0 matvec (lanebcast over acc, same order as k2) + poly +
//                bf16 feats write + readout0  -> agg global round-trip DELETED.
//   L1 epilogue: node1 math (wave 0 only; uses accA[0]/accB[0] + feats m0 row).
// Accumulation order and all expressions unchanged -> absmax bit-identical.
// launch_bounds(256,4): r9 — higher caps VGPR -> scratch spills.
template <bool L0>
__global__ __launch_bounds__(256, 4)
void fused_edge_kernel(const unsigned short* __restrict__ Hb,
                       const unsigned short* __restrict__ w2fl,
                       const float* __restrict__ Y,
                       const unsigned short* __restrict__ featsIn, // bf16 [n][m][f] (L1)
                       const float* __restrict__ w_embed,
                       const int* __restrict__ specie,
                       const int* __restrict__ offs,
                       const int* __restrict__ eidx,
                       const int* __restrict__ snd_csr,
                       const int* __restrict__ rcv_csr,
                       const float* __restrict__ w_skipL,   // layer's (S,4,F,F)
                       const float* __restrict__ w_polyL,   // layer's (3,S,F)
                       const float* __restrict__ w_read0,   // L0 only
                       const float* __restrict__ w_mlp1,    // L1 only
                       const float* __restrict__ w_mlp2,    // L1 only
                       unsigned short* __restrict__ featsOut, // L0 only
                       float* __restrict__ out, int N) {
    __shared__ float R_lds[16 * 532];   // 34,048 B
    __shared__ float ysL[16][16];
    __shared__ int   ssL[16];           // L0: sender specie; L1: sender id
    __shared__ int   rsL[16];
    __shared__ float h0LA[64];
    __shared__ float h0LB[64];
    const int tid = threadIdx.x;
    const int wave = tid >> 6, lane = tid & 63;
    const int lo = lane & 15, hi = lane >> 4;
    const int n0 = blockIdx.x * 2;
    const int segS = offs[n0], segE = offs[n0 + 2];
    const int mbase = wave * 4;

    float accA[4] = {0.f, 0.f, 0.f, 0.f};
    float accB[4] = {0.f, 0.f, 0.f, 0.f};

    for (int base = segS; base < segE; base += 16) {
        const int bend = (base + 16 < segE) ? base + 16 : segE;
        const int tcnt = bend - base;
        // ---------- phase 0: preload Y rows + metadata ----------
        {
            const int t = tid >> 4, m = tid & 15;
            const int pos = base + t;
            const int cp = (pos < segE) ? pos : (segE - 1);
            ysL[t][m] = Y[(size_t)eidx[cp] * 16 + m];
            if (tid < 16) {
                const int p2 = base + tid;
                const int c2 = (p2 < segE) ? p2 : (segE - 1);
                const int s = snd_csr[c2];
                ssL[tid] = L0 ? specie[s] : s;
                rsL[tid] = rcv_csr[c2];
            }
        }
        // ---------- phase 1: MFMA 16 edges x 512; fp32 -> LDS ----------
        {
            const int pos = base + lo;
            const int cp = (pos < segE) ? pos : (segE - 1);
            const int eid = eidx[cp];
            const unsigned short* hrow = Hb + (size_t)eid * 64;
            const short8v a0 = *(const short8v*)(hrow + hi * 8);
            const short8v a1 = *(const short8v*)(hrow + 32 + hi * 8);
            f32x4 c16[8];
#pragma unroll
            for (int i = 0; i < 8; i++) c16[i] = (f32x4)(0.f);
#pragma unroll
            for (int tt = 0; tt < 8; tt++) {
                const int ct = wave * 8 + tt;
                const short8v b0 = *(const short8v*)(w2fl + ct * 1024 + lane * 8);
                const short8v b1 = *(const short8v*)(w2fl + ct * 1024 + 512 + lane * 8);
                c16[tt] = __builtin_amdgcn_mfma_f32_16x16x32_bf16(a0, b0, c16[tt], 0, 0, 0);
                c16[tt] = __builtin_amdgcn_mfma_f32_16x16x32_bf16(a1, b1, c16[tt], 0, 0, 0);
            }
            const int lc = lo & 7;
#pragma unroll
            for (int tt = 0; tt < 8; tt++) {
                const int ct = wave * 8 + tt;
                const int f = ct * 2 + (lo >> 3);
#pragma unroll
                for (int r = 0; r < 4; r++) {
                    const int el = hi * 4 + r;
                    R_lds[el * 532 + lc * 66 + f] = c16[tt][r];
                }
            }
        }
        __syncthreads();
        // ---------- phase 2: weight + per-node accumulate, depth-1 prefetch ----------
        {
            float ps0, pf[4] = {0.f, 0.f, 0.f, 0.f};
            if (L0) {
                ps0 = w_embed[ssL[0] * 64 + lane];
            } else {
                const unsigned short* f_ = featsIn + (size_t)ssL[0] * 1024;
                ps0 = bf16tof(f_[lane]);
#pragma unroll
                for (int j = 0; j < 4; j++) pf[j] = bf16tof(f_[(mbase + j) * 64 + lane]);
            }
            for (int k = 0; k < tcnt; k++) {
                float ns0 = 0.f, nf[4] = {0.f, 0.f, 0.f, 0.f};
                const int kn = (k + 1 < tcnt) ? k + 1 : k;
                if (L0) {
                    ns0 = w_embed[ssL[kn] * 64 + lane];
                } else {
                    const unsigned short* f_ = featsIn + (size_t)ssL[kn] * 1024;
                    ns0 = bf16tof(f_[lane]);
#pragma unroll
                    for (int j = 0; j < 4; j++) nf[j] = bf16tof(f_[(mbase + j) * 64 + lane]);
                }
                const int node = rsL[k];
                const float* Rt = R_lds + k * 532;
                if (node == n0) {
#pragma unroll
                    for (int j = 0; j < 4; j++) {
                        const int m = mbase + j;
                        const int l = l_of_m(m);
                        const float r0 = Rt[(2 * l) * 66 + lane];
                        const float r1 = Rt[(2 * l + 1) * 66 + lane];
                        const float ym = ysL[k][m];
                        const float fsm = L0 ? ((m == 0) ? ps0 : 0.f) : pf[j];
                        accA[j] += r0 * ps0 * ym + r1 * fsm;
                    }
                } else {
#pragma unroll
                    for (int j = 0; j < 4; j++) {
                        const int m = mbase + j;
                        const int l = l_of_m(m);
                        const float r0 = Rt[(2 * l) * 66 + lane];
                        const float r1 = Rt[(2 * l + 1) * 66 + lane];
                        const float ym = ysL[k][m];
                        const float fsm = L0 ? ((m == 0) ? ps0 : 0.f) : pf[j];
                        accB[j] += r0 * ps0 * ym + r1 * fsm;
                    }
                }
                ps0 = ns0;
                if (!L0) {
#pragma unroll
                    for (int j = 0; j < 4; j++) pf[j] = nf[j];
                }
            }
        }
        __syncthreads();
    }

    // ================= epilogue: node-level math in-kernel =================
    const int nA = n0, nB = n0 + 1;
    const int spA = specie[nA], spB = specie[nB];
    const int g = lane;

    if (L0) {
        // ---- node0: matvec over acc (same lanebcast order as k2) ----
        float aA[4], aB[4];
#pragma unroll
        for (int j = 0; j < 4; j++) { aA[j] = accA[j] * 0.25f; aB[j] = accB[j] * 0.25f; }
        const float* WA = w_skipL + (size_t)spA * 4 * F * F;
        const float* WB = w_skipL + (size_t)spB * 4 * F * F;
        float hA[4] = {0.f, 0.f, 0.f, 0.f};
        float hB[4] = {0.f, 0.f, 0.f, 0.f};
        if (wave == 0) {            // m0 -> l0 ; m1..3 -> l1
            const float *WA0 = WA, *WA1 = WA + 4096, *WB0 = WB, *WB1 = WB + 4096;
#pragma unroll
            for (int f = 0; f < 64; f++) {
                const float wa0 = WA0[f * 64 + g], wa1 = WA1[f * 64 + g];
                const float wb0 = WB0[f * 64 + g], wb1 = WB1[f * 64 + g];
                hA[0] += lanebcast(aA[0], f) * wa0;
                hA[1] += lanebcast(aA[1], f) * wa1;
                hA[2] += lanebcast(aA[2], f) * wa1;
                hA[3] += lanebcast(aA[3], f) * wa1;
                hB[0] += lanebcast(aB[0], f) * wb0;
                hB[1] += lanebcast(aB[1], f) * wb1;
                hB[2] += lanebcast(aB[2], f) * wb1;
                hB[3] += lanebcast(aB[3], f) * wb1;
            }
        } else if (wave == 1) {     // m4..7 -> l2
            const float *WA2 = WA + 8192, *WB2 = WB + 8192;
#pragma unroll
            for (int f = 0; f < 64; f++) {
                const float wa2 = WA2[f * 64 + g], wb2 = WB2[f * 64 + g];
                hA[0] += lanebcast(aA[0], f) * wa2;
                hA[1] += lanebcast(aA[1], f) * wa2;
                hA[2] += lanebcast(aA[2], f) * wa2;
                hA[3] += lanebcast(aA[3], f) * wa2;
                hB[0] += lanebcast(aB[0], f) * wb2;
                hB[1] += lanebcast(aB[1], f) * wb2;
                hB[2] += lanebcast(aB[2], f) * wb2;
                hB[3] += lanebcast(aB[3], f) * wb2;
            }
        } else if (wave == 2) {     // m8 -> l2 ; m9..11 -> l3
            const float *WA2 = WA + 8192, *WA3 = WA + 12288;
            const float *WB2 = WB + 8192, *WB3 = WB + 12288;
#pragma unroll
            for (int f = 0; f < 64; f++) {
                const float wa2 = WA2[f * 64 + g], wa3 = WA3[f * 64 + g];
                const float wb2 = WB2[f * 64 + g], wb3 = WB3[f * 64 + g];
                hA[0] += lanebcast(aA[0], f) * wa2;
                hA[1] += lanebcast(aA[1], f) * wa3;
                hA[2] += lanebcast(aA[2], f) * wa3;
                hA[3] += lanebcast(aA[3], f) * wa3;
                hB[0] += lanebcast(aB[0], f) * wb2;
                hB[1] += lanebcast(aB[1], f) * wb3;
                hB[2] += lanebcast(aB[2], f) * wb3;
                hB[3] += lanebcast(aB[3], f) * wb3;
            }
        } else {                    // m12..15 -> l3
            const float *WA3 = WA + 12288, *WB3 = WB + 12288;
#pragma unroll
            for (int f = 0; f < 64; f++) {
                const float wa3 = WA3[f * 64 + g], wb3 = WB3[f * 64 + g];
                hA[0] += lanebcast(aA[0], f) * wa3;
                hA[1] += lanebcast(aA[1], f) * wa3;
                hA[2] += lanebcast(aA[2], f) * wa3;
                hA[3] += lanebcast(aA[3], f) * wa3;
                hB[0] += lanebcast(aB[0], f) * wb3;
                hB[1] += lanebcast(aB[1], f) * wb3;
                hB[2] += lanebcast(aB[2], f) * wb3;
                hB[3] += lanebcast(aB[3], f) * wb3;
            }
        }
        if (wave == 0) { h0LA[g] = hA[0]; h0LB[g] = hB[0]; }
        __syncthreads();
        const float sA = h0LA[g], sB = h0LB[g];
        const float c0A = w_polyL[(0 * NSPEC + spA) * F + g];
        const float c1A = w_polyL[(1 * NSPEC + spA) * F + g];
        const float c2A = w_polyL[(2 * NSPEC + spA) * F + g];
        const float scaleA = c0A + c1A * sA + c2A * sA * sA;
        const float c0B = w_polyL[(0 * NSPEC + spB) * F + g];
        const float c1B = w_polyL[(1 * NSPEC + spB) * F + g];
        const float c2B = w_polyL[(2 * NSPEC + spB) * F + g];
        const float scaleB = c0B + c1B * sB + c2B * sB * sB;
#pragma unroll
        for (int j = 0; j < 4; j++) {
            featsOut[(size_t)nA * 1024 + (mbase + j) * 64 + g] = bf16bits(hA[j] * scaleA);
            featsOut[(size_t)nB * 1024 + (mbase + j) * 64 + g] = bf16bits(hB[j] * scaleB);
        }
        if (wave == 0) {
            float vA = (hA[0] * scaleA) * w_read0[g];
            float vB = (hB[0] * scaleB) * w_read0[g];
#pragma unroll
            for (int off = 32; off > 0; off >>= 1) {
                vA += __shfl_down(vA, off);
                vB += __shfl_down(vB, off);
            }
            if (g == 0) {
                out[(size_t)nA * 2 + 0] = vA;
                out[(size_t)nB * 2 + 0] = vB;
            }
        }
    } else {
        // ---- node1 (wave 0 only): needs acc[0] (m=0 row) + feats m0 row ----
        if (wave == 0) {
            // node A
            {
                const float* W0 = w_skipL + (size_t)spA * 4 * F * F;
                const float fv = bf16tof(featsIn[(size_t)nA * 1024 + lane]);
                float sc0 = 0.0f;
#pragma unroll
                for (int f = 0; f < F; f++) sc0 += lanebcast(fv, f) * W0[f * F + lane];
                const float h0 = accA[0] * 0.25f;
                const float c0 = w_polyL[(0 * NSPEC + spA) * F + lane];
                const float c1 = w_polyL[(1 * NSPEC + spA) * F + lane];
                const float c2 = w_polyL[(2 * NSPEC + spA) * F + lane];
                const float scale = c0 + c1 * h0 + c2 * h0 * h0;
                const float f2 = h0 * scale + sc0;
                float mac = 0.0f;
#pragma unroll
                for (int gg = 0; gg < F; gg++) {
                    const float fg = lanebcast(f2, gg);
                    if (lane < HID_READ) mac += fg * w_mlp1[gg * HID_READ + lane];
                }
                float o = 0.0f;
                if (lane < HID_READ) o = silu(mac) * w_mlp2[lane];
#pragma unroll
                for (int off = 32; off > 0; off >>= 1) o += __shfl_down(o, off);
                if (lane == 0) out[(size_t)nA * 2 + 1] = o;
            }
            // node B
            {
                const float* W0 = w_skipL + (size_t)spB * 4 * F * F;
                const float fv = bf16tof(featsIn[(size_t)nB * 1024 + lane]);
                float sc0 = 0.0f;
#pragma unroll
                for (int f = 0; f < F; f++) sc0 += lanebcast(fv, f) * W0[f * F + lane];
                const float h0 = accB[0] * 0.25f;
                const float c0 = w_polyL[(0 * NSPEC + spB) * F + lane];
                const float c1 = w_polyL[(1 * NSPEC + spB) * F + lane];
                const float c2 = w_polyL[(2 * NSPEC + spB) * F + lane];
                const float scale = c0 + c1 * h0 + c2 * h0 * h0;
                const float f2 = h0 * scale + sc0;
                float mac = 0.0f;
#pragma unroll
                for (int gg = 0; gg < F; gg++) {
                    const float fg = lanebcast(f2, gg);
                    if (lane < HID_READ) mac += fg * w_mlp1[gg * HID_READ + lane];
                }
                float o = 0.0f;
                if (lane < HID_READ) o = silu(mac) * w_mlp2[lane];
#pragma unroll
                for (int off = 32; off > 0; off >>= 1) o += __shfl_down(o, off);
                if (lane == 0) out[(size_t)nB * 2 + 1] = o;
            }
        }
    }
}

// ========== K2 (FALLBACK ONLY): node0 + optional geo/H tail ==========
__global__ void k2_kernel(const float* __restrict__ agg,
                          const int* __restrict__ specie,
                          const float* __restrict__ w_skip0,
                          const float* __restrict__ w_poly0,
                          const float* __restrict__ w_read0,
                          float* __restrict__ featsF,
                          float* __restrict__ out, int N) {
    const int n = blockIdx.x;
    const int g = threadIdx.x & 63;
    const int mb = threadIdx.x >> 6;
    const int sp = specie[n];
    const float* W = w_skip0 + (size_t)sp * 4 * F * F;

    float areg[4];
#pragma unroll
    for (int j = 0; j < 4; j++) areg[j] = agg[(size_t)n * 1024 + (mb * 4 + j) * 64 + g];

    float h[4] = {0.f, 0.f, 0.f, 0.f};
    if (mb == 0) {
        const float* W0 = W;
        const float* W1 = W + 4096;
#pragma unroll
        for (int f = 0; f < 64; f++) {
            const float w0 = W0[f * 64 + g];
            const float w1 = W1[f * 64 + g];
            h[0] += lanebcast(areg[0], f) * w0;
            h[1] += lanebcast(areg[1], f) * w1;
            h[2] += lanebcast(areg[2], f) * w1;
            h[3] += lanebcast(areg[3], f) * w1;
        }
    } else if (mb == 1) {
        const float* W2 = W + 8192;
#pragma unroll
        for (int f = 0; f < 64; f++) {
            const float w2 = W2[f * 64 + g];
            h[0] += lanebcast(areg[0], f) * w2;
            h[1] += lanebcast(areg[1], f) * w2;
            h[2] += lanebcast(areg[2], f) * w2;
            h[3] += lanebcast(areg[3], f) * w2;
        }
    } else if (mb == 2) {
        const float* W2 = W + 8192;
        const float* W3 = W + 12288;
#pragma unroll
        for (int f = 0; f < 64; f++) {
            const float w2 = W2[f * 64 + g];
            const float w3 = W3[f * 64 + g];
            h[0] += lanebcast(areg[0], f) * w2;
            h[1] += lanebcast(areg[1], f) * w3;
            h[2] += lanebcast(areg[2], f) * w3;
            h[3] += lanebcast(areg[3], f) * w3;
        }
    } else {
        const float* W3 = W + 12288;
#pragma unroll
        for (int f = 0; f < 64; f++) {
            const float w3 = W3[f * 64 + g];
            h[0] += lanebcast(areg[0], f) * w3;
            h[1] += lanebcast(areg[1], f) * w3;
            h[2] += lanebcast(areg[2], f) * w3;
            h[3] += lanebcast(areg[3], f) * w3;
        }
    }

    __shared__ float h0L[64];
    if (mb == 0) h0L[g] = h[0];
    __syncthreads();
    const float s = h0L[g];
    const float c0 = w_poly0[(0 * NSPEC + sp) * F + g];
    const float c1 = w_poly0[(1 * NSPEC + sp) * F + g];
    const float c2 = w_poly0[(2 * NSPEC + sp) * F + g];
    const float scale = c0 + c1 * s + c2 * s * s;
    float f0val = 0.0f;
#pragma unroll
    for (int j = 0; j < 4; j++) {
        const int m = mb * 4 + j;
        const float fv = h[j] * scale;
        featsF[(size_t)n * 1024 + m * 64 + g] = fv;
        if (m == 0) f0val = fv;
    }
    if (mb == 0) {
        float v = f0val * w_read0[g];
#pragma unroll
        for (int off = 32; off > 0; off >>= 1) v += __shfl_down(v, off);
        if (g == 0) out[(size_t)n * 2 + 0] = v;
    }
}

// ---------- fallback node1 (fp32 feats) ----------
__global__ void node1f_kernel(const float* __restrict__ agg,
                              const float* __restrict__ feats,
                              const int* __restrict__ specie,
                              const float* __restrict__ w_skip1,
                              const float* __restrict__ w_poly1,
                              const float* __restrict__ w_mlp1,
                              const float* __restrict__ w_mlp2,
                              float* __restrict__ out, int N) {
    const int wave = threadIdx.x >> 6;
    const int lane = threadIdx.x & 63;
    const int n = blockIdx.x * 4 + wave;
    const int sp = specie[n];
    const float* W0 = w_skip1 + (size_t)sp * 4 * F * F;
    const float fv = feats[(size_t)n * 1024 + lane];
    float sc0 = 0.0f;
#pragma unroll 8
    for (int f = 0; f < F; f++) {
        const float ff = __shfl(fv, f);
        sc0 += ff * W0[f * F + lane];
    }
    const float h0 = agg[(size_t)n * 1024 + lane];
    const float c0 = w_poly1[(0 * NSPEC + sp) * F + lane];
    const float c1 = w_poly1[(1 * NSPEC + sp) * F + lane];
    const float c2 = w_poly1[(2 * NSPEC + sp) * F + lane];
    const float scale = c0 + c1 * h0 + c2 * h0 * h0;
    const float f2 = h0 * scale + sc0;
    float acc = 0.0f;
#pragma unroll 8
    for (int gg = 0; gg < F; gg++) {
        const float fg = __shfl(f2, gg);
        if (lane < HID_READ) acc += fg * w_mlp1[gg * HID_READ + lane];
    }
    float o = 0.0f;
    if (lane < HID_READ) o = silu(acc) * w_mlp2[lane];
#pragma unroll
    for (int off = 32; off > 0; off >>= 1) o += __shfl_down(o, off);
    if (lane == 0) out[(size_t)n * 2 + 1] = o;
}

// ---------- fallback (round-1, known-passing) edge kernel ----------
__global__ void edge_kernel(const float* __restrict__ Y, const float* __restrict__ Remb,
                            const float* __restrict__ feats_t,
                            const int* __restrict__ senders, const int* __restrict__ receivers,
                            const float* __restrict__ w1, const float* __restrict__ w2,
                            float* __restrict__ agg_t, int E) {
    const int wave = threadIdx.x >> 6;
    const int lane = threadIdx.x & 63;
    const int e = blockIdx.x * 4 + wave;
    __shared__ float hbuf[4][64];
    const float* remb = Remb + (size_t)e * NRAD;
    float acc = 0.0f;
#pragma unroll
    for (int k = 0; k < NRAD; k++) acc += remb[k] * w1[k * F + lane];
    hbuf[wave][lane] = silu(acc);
    __syncthreads();
    float r8[8] = {0.f, 0.f, 0.f, 0.f, 0.f, 0.f, 0.f, 0.f};
    const float* w2base = w2 + lane * 8;
#pragma unroll 8
    for (int j = 0; j < HID_R; j++) {
        float hj = hbuf[wave][j];
        const float4 a = *(const float4*)(w2base + j * 512);
        const float4 b = *(const float4*)(w2base + j * 512 + 4);
        r8[0] += hj * a.x; r8[1] += hj * a.y; r8[2] += hj * a.z; r8[3] += hj * a.w;
        r8[4] += hj * b.x; r8[5] += hj * b.y; r8[6] += hj * b.z; r8[7] += hj * b.w;
    }
    const int snd = senders[e];
    const int rcv = receivers[e];
    const float* fsrc = feats_t + (size_t)snd * (F * LDIM);
    float* adst = agg_t + (size_t)rcv * (F * LDIM);
    const float s0 = fsrc[lane];
    const float* Ye = Y + (size_t)e * 16;
#pragma unroll
    for (int m = 0; m < LDIM; m++) {
        const int l = l_of_m(m);
        const float ym = Ye[m];
        const float fsm = fsrc[m * F + lane];
        const float val = r8[l * 2 + 0] * s0 * ym + r8[l * 2 + 1] * fsm;
        atomicAdd(adst + m * F + lane, val * 0.25f);
    }
}

static inline size_t alignup(size_t x) { return (x + 255) & ~(size_t)255; }

extern "C" void kernel_launch(void* const* d_in, const int* in_sizes, int n_in,
                              void* d_out, int out_size, void* d_ws, size_t ws_size,
                              hipStream_t stream) {
    const float* vectors   = (const float*)d_in[0];
    const int*   specie    = (const int*)d_in[1];
    const int*   senders   = (const int*)d_in[2];
    const int*   receivers = (const int*)d_in[3];
    const float* w_embed   = (const float*)d_in[4];
    const float* w_r1      = (const float*)d_in[5];
    const float* w_r2      = (const float*)d_in[6];
    const float* w_skip    = (const float*)d_in[7];
    const float* w_poly    = (const float*)d_in[8];
    const float* w_read0   = (const float*)d_in[9];
    const float* w_mlp1    = (const float*)d_in[10];
    const float* w_mlp2    = (const float*)d_in[11];
    float* out = (float*)d_out;

    const int E = in_sizes[0] / 3;   // 160000
    const int N = in_sizes[1];       // 10000
    const int ngeo = (E + 255) / 256;

    // ---- fast-path workspace layout (~74 MB, agg deleted) ----
    char* base = (char*)d_ws;
    size_t off = 0;
    float* Y      = (float*)(base + off); off += alignup((size_t)E * 16 * sizeof(float));
    unsigned short* featsB = (unsigned short*)(base + off); off += alignup((size_t)N * F * LDIM * sizeof(unsigned short));
    unsigned short* Hb0 = (unsigned short*)(base + off); off += alignup((size_t)E * 64 * sizeof(unsigned short));
    unsigned short* Hb1 = (unsigned short*)(base + off); off += alignup((size_t)E * 64 * sizeof(unsigned short));
    int* cnt      = (int*)(base + off);   off += alignup((size_t)N * sizeof(int));
    int* cur      = (int*)(base + off);   off += alignup((size_t)N * sizeof(int));
    int* offs     = (int*)(base + off);   off += alignup((size_t)(N + 1) * sizeof(int));
    int* eidx     = (int*)(base + off);   off += alignup((size_t)E * sizeof(int));
    int* snd_csr  = (int*)(base + off);   off += alignup((size_t)E * sizeof(int));
    int* rcv_csr  = (int*)(base + off);   off += alignup((size_t)E * sizeof(int));
    unsigned short* w2f = (unsigned short*)(base + off); off += alignup((size_t)2 * 32768 * sizeof(unsigned short));
    const size_t need = off;

    const size_t aggBytes = (size_t)N * F * LDIM * sizeof(float);

    if (ws_size >= need && (N & 1) == 0) {
        // =========== fast path: 6 dispatches, no agg round-trip ===========
        hipMemsetAsync(cnt, 0, (size_t)N * sizeof(int), stream);
        hipMemsetAsync(cur, 0, (size_t)N * sizeof(int), stream);
        k1_kernel<<<ngeo + 2, 256, 0, stream>>>(vectors, w_r1, w_r2, receivers,
                                                Y, Hb0, Hb1, cnt, w2f, E, ngeo);
        scan_kernel<<<1, 1024, 0, stream>>>(cnt, offs, N);
        scatter_kernel<<<ngeo, 256, 0, stream>>>(receivers, senders, offs, cur,
                                                 eidx, snd_csr, rcv_csr, E);
        // ---- layer 0 (+ node0 epilogue) ----
        fused_edge_kernel<true><<<N / 2, 256, 0, stream>>>(
            Hb0, w2f, Y, nullptr, w_embed, specie, offs, eidx, snd_csr, rcv_csr,
            w_skip + (size_t)0 * NSPEC * 4 * F * F,
            w_poly + (size_t)0 * 3 * NSPEC * F,
            w_read0, nullptr, nullptr, featsB, out, N);
        // ---- layer 1 (+ node1 epilogue) ----
        fused_edge_kernel<false><<<N / 2, 256, 0, stream>>>(
            Hb1, w2f + 32768, Y, featsB, w_embed, specie, offs, eidx, snd_csr, rcv_csr,
            w_skip + (size_t)1 * NSPEC * 4 * F * F,
            w_poly + (size_t)1 * 3 * NSPEC * F,
            nullptr, w_mlp1, w_mlp2, nullptr, out, N);
    } else {
        // =========== fallback: round-1 atomic path (fp32 throughout) ===========
        size_t fo = 0;
        float* Yf    = (float*)(base + fo); fo += alignup((size_t)E * 16 * sizeof(float));
        float* Remb  = (float*)(base + fo); fo += alignup((size_t)E * NRAD * sizeof(float));
        float* featsF= (float*)(base + fo); fo += alignup((size_t)N * F * LDIM * sizeof(float));
        float* aggF  = (float*)(base + fo);

        geo_kernel<<<ngeo, 256, 0, stream>>>(vectors, Yf, Remb, E);
        init_feats_kernel<<<N, 256, 0, stream>>>(w_embed, specie, featsF, N);
        hipMemsetAsync(aggF, 0, aggBytes, stream);
        edge_kernel<<<E / 4, 256, 0, stream>>>(Yf, Remb, featsF, senders, receivers,
                                               w_r1, w_r2, aggF, E);
        k2_kernel<<<N, 256, 0, stream>>>(aggF, specie,
                                         w_skip + (size_t)0 * NSPEC * 4 * F * F,
                                         w_poly + (size_t)0 * 3 * NSPEC * F,
                                         w_read0, featsF, out, N);
        hipMemsetAsync(aggF, 0, aggBytes, stream);
        edge_kernel<<<E / 4, 256, 0, stream>>>(Yf, Remb, featsF, senders, receivers,
                                               w_r1 + NRAD * HID_R, w_r2 + HID_R * 512,
                                               aggF, E);
        node1f_kernel<<<N / 4, 256, 0, stream>>>(aggF, featsF, specie,
                                                 w_skip + (size_t)1 * NSPEC * 4 * F * F,
                                                 w_poly + (size_t)1 * 3 * NSPEC * F,
                                                 w_mlp1, w_mlp2, out, N);
    }
}

// Round 19
// 355.708 us; speedup vs baseline: 1.0806x; 1.0806x over previous
//
#include <hip/hip_runtime.h>
#include <math.h>

#define F 64
#define LDIM 16
#define NRAD 8
#define HID_R 64
#define HID_READ 32
#define NSPEC 10

typedef __attribute__((ext_vector_type(8))) short short8v;
typedef __attribute__((ext_vector_type(4))) float f32x4;

__device__ __forceinline__ int l_of_m(int m) {
    return (m == 0) ? 0 : (m < 4) ? 1 : (m < 9) ? 2 : 3;
}
__device__ __forceinline__ float silu(float x) { return x / (1.0f + __expf(-x)); }
__device__ __forceinline__ unsigned short bf16bits(float x) {
    unsigned int u = __float_as_uint(x);
    u += 0x7fffu + ((u >> 16) & 1u);   // RNE
    return (unsigned short)(u >> 16);
}
__device__ __forceinline__ float bf16tof(unsigned short b) {
    return __uint_as_float(((unsigned int)b) << 16);
}
// Bit-exact lane broadcast on the VALU pipe (v_readlane_b32), NOT the DS pipe.
// BITCAST through uint — a float arg would be float->uint CONVERTED (r6/7 bug).
__device__ __forceinline__ float lanebcast(float v, int l) {
    return __uint_as_float(__builtin_amdgcn_readlane(__float_as_uint(v), l));
}

__device__ __forceinline__ void geo_core(const float* __restrict__ vectors, int e,
                                         float* Ye_out, float* remb_out) {
    float vx = vectors[e * 3 + 0];
    float vy = vectors[e * 3 + 1];
    float vz = vectors[e * 3 + 2];
    float r = sqrtf(vx * vx + vy * vy + vz * vz + 1e-12f);
    float x = vx / r, y = vy / r, z = vz / r;
    float r2 = x * x + y * y + z * z;
    Ye_out[0]  = 1.0f;  Ye_out[1] = x;  Ye_out[2] = y;  Ye_out[3] = z;
    Ye_out[4]  = x * y; Ye_out[5] = y * z; Ye_out[6] = 3.0f * z * z - r2; Ye_out[7] = x * z;
    Ye_out[8]  = x * x - y * y;
    Ye_out[9]  = y * (3.0f * x * x - y * y);
    Ye_out[10] = x * y * z;
    Ye_out[11] = y * (5.0f * z * z - r2);
    Ye_out[12] = z * (5.0f * z * z - 3.0f * r2);
    Ye_out[13] = x * (5.0f * z * z - r2);
    Ye_out[14] = z * (x * x - y * y);
    Ye_out[15] = x * (x * x - 3.0f * y * y);
    float u = r / 5.0f;
    float env = (u < 1.0f) ? (1.0f - u) * (1.0f - u) * (1.0f + 2.0f * u) : 0.0f;
    float inv = env / (u + 1e-6f);
    const float PI = 3.14159265358979323846f;
#pragma unroll
    for (int k = 1; k <= NRAD; k++) remb_out[k - 1] = sinf(PI * (float)k * u) * inv;
}

__device__ __forceinline__ void hid_write(const float* remb, const float* w1,
                                          unsigned short* __restrict__ Hb, int e) {
    float h[HID_R];
#pragma unroll
    for (int j = 0; j < HID_R; j++) {
        float a = 0.0f;
#pragma unroll
        for (int k = 0; k < NRAD; k++) a += remb[k] * w1[k * HID_R + j];
        h[j] = silu(a);
    }
    unsigned int* dst = (unsigned int*)(Hb + (size_t)e * HID_R);
#pragma unroll
    for (int w = 0; w < 32; w++) {
        unsigned int lo = bf16bits(h[2 * w]);
        unsigned int hi = bf16bits(h[2 * w + 1]);
        dst[w] = lo | (hi << 16);
    }
}

// =========== K1: geo+H(L0)+hist  |  conv_w2 (2 tail blocks) ===========
__global__ void k1_kernel(const float* __restrict__ vectors,
                          const float* __restrict__ w_r1,   // (2,8,64)
                          const float* __restrict__ w_r2,   // (2,64,512)
                          const int* __restrict__ receivers,
                          float* __restrict__ Y,
                          unsigned short* __restrict__ Hb,
                          int* __restrict__ cnt,
                          unsigned short* __restrict__ w2f,
                          int E, int ngeo) {
    const int bid = blockIdx.x;
    if (bid >= ngeo) {
        const int layer = bid - ngeo;
        const float* src = w_r2 + (size_t)layer * HID_R * 512;
        unsigned short* dst = w2f + (size_t)layer * 32768;
        for (int idx = threadIdx.x; idx < 32768; idx += 256) {
            int j    = idx & 7;
            int lane = (idx >> 3) & 63;
            int ks   = (idx >> 9) & 1;
            int ct   = idx >> 10;
            int k    = ks * 32 + (lane >> 4) * 8 + j;
            int col  = ct * 16 + (lane & 15);
            dst[idx] = bf16bits(src[k * 512 + col]);
        }
        return;
    }
    const int e = bid * 256 + threadIdx.x;
    if (e >= E) return;
    atomicAdd(&cnt[receivers[e]], 1);
    float ye[16], remb[NRAD];
    geo_core(vectors, e, ye, remb);
    float4* Yd = (float4*)(Y + (size_t)e * 16);
    Yd[0] = make_float4(ye[0], ye[1], ye[2], ye[3]);
    Yd[1] = make_float4(ye[4], ye[5], ye[6], ye[7]);
    Yd[2] = make_float4(ye[8], ye[9], ye[10], ye[11]);
    Yd[3] = make_float4(ye[12], ye[13], ye[14], ye[15]);
    hid_write(remb, w_r1, Hb, e);
}

// ---------- fallback geo ----------
__global__ void geo_kernel(const float* __restrict__ vectors,
                           float* __restrict__ Y, float* __restrict__ Remb, int E) {
    int e = blockIdx.x * 256 + threadIdx.x;
    if (e >= E) return;
    float ye[16], remb[NRAD];
    geo_core(vectors, e, ye, remb);
#pragma unroll
    for (int m = 0; m < 16; m++) Y[(size_t)e * 16 + m] = ye[m];
#pragma unroll
    for (int k = 0; k < NRAD; k++) Remb[(size_t)e * NRAD + k] = remb[k];
}

// ---------- CSR scan (1024 threads — r13's fix) / scatter ----------
__global__ void scan_kernel(const int* __restrict__ cnt, int* __restrict__ offs, int N) {
    __shared__ int buf[1024];
    __shared__ int carry;
    int t = threadIdx.x;
    if (t == 0) carry = 0;
    __syncthreads();
    for (int base = 0; base < N; base += 1024) {
        int v = (base + t < N) ? cnt[base + t] : 0;
        buf[t] = v;
        __syncthreads();
#pragma unroll
        for (int off = 1; off < 1024; off <<= 1) {
            int x = (t >= off) ? buf[t - off] : 0;
            __syncthreads();
            buf[t] += x;
            __syncthreads();
        }
        if (base + t < N) offs[base + t] = carry + buf[t] - v;   // exclusive
        __syncthreads();
        if (t == 0) carry += buf[1023];
        __syncthreads();
    }
    if (t == 0) offs[N] = carry;
}

__global__ void scatter_kernel(const int* __restrict__ receivers,
                               const int* __restrict__ senders,
                               const int* __restrict__ offs, int* __restrict__ cur,
                               int* __restrict__ eidx, int* __restrict__ snd_csr,
                               int* __restrict__ rcv_csr, int E) {
    int e = blockIdx.x * 256 + threadIdx.x;
    if (e >= E) return;
    int r = receivers[e];
    int pos = atomicAdd(&cur[r], 1);
    int t = offs[r] + pos;
    eidx[t] = e;
    snd_csr[t] = senders[e];
    rcv_csr[t] = r;
}

// ---------- feats init (fallback only, fp32) ----------
__global__ void init_feats_kernel(const float* __restrict__ w_embed,
                                  const int* __restrict__ specie,
                                  float* __restrict__ feats_t, int N) {
    int n = blockIdx.x;
    int sp = specie[n];
    for (int i = threadIdx.x; i < F * LDIM; i += 256) {
        int m = i >> 6;
        int f = i & 63;
        feats_t[(size_t)n * (F * LDIM) + i] = (m == 0) ? w_embed[sp * F + f] : 0.0f;
    }
}

// ========== fused edge kernel (r17 configuration — measured optimum) ==========
// r15's edge structure (fp32 R scalar LDS 532/66, linear [n][m][f] bf16 feats,
// all 4 waves per edge, wave owns 4 m's) + depth-2 prefetch (named sets A/B).
// Falsified alternatives: r12 wave-per-node (-4x parallelism), r13 transposed
// feats (uncoalesced), r14 bf16-R+occupancy push (occupancy not LDS-capped),
// r16 DS-vectorization (DS not binding), r18 node-math epilogue fusion
// (serial tail + occupancy drop). launch_bounds(256,4): r9 — higher caps
// VGPR -> scratch spills.
template <bool L0>
__global__ __launch_bounds__(256, 4)
void fused_edge_kernel(const unsigned short* __restrict__ Hb,
                       const unsigned short* __restrict__ w2fl,
                       const float* __restrict__ Y,
                       const unsigned short* __restrict__ featsB,  // bf16 [n][m][f] (L1)
                       const float* __restrict__ w_embed,
                       const int* __restrict__ specie,
                       const int* __restrict__ offs,
                       const int* __restrict__ eidx,
                       const int* __restrict__ snd_csr,
                       const int* __restrict__ rcv_csr,
                       float* __restrict__ agg, int N) {
    __shared__ float R_lds[16 * 532];   // 34,048 B
    __shared__ float ysL[16][16];
    __shared__ int   ssL[16];           // L0: sender specie; L1: sender id
    __shared__ int   rsL[16];
    const int tid = threadIdx.x;
    const int wave = tid >> 6, lane = tid & 63;
    const int lo = lane & 15, hi = lane >> 4;
    const int n0 = blockIdx.x * 2;
    const int segS = offs[n0], segE = offs[n0 + 2];
    const int mbase = wave * 4;

    int cur = -1;
    float acc[4] = {0.f, 0.f, 0.f, 0.f};

    for (int base = segS; base < segE; base += 16) {
        const int bend = (base + 16 < segE) ? base + 16 : segE;
        const int tcnt = bend - base;
        // ---------- phase 0: preload Y rows + metadata ----------
        {
            const int t = tid >> 4, m = tid & 15;
            const int pos = base + t;
            const int cp = (pos < segE) ? pos : (segE - 1);
            ysL[t][m] = Y[(size_t)eidx[cp] * 16 + m];
            if (tid < 16) {
                const int p2 = base + tid;
                const int c2 = (p2 < segE) ? p2 : (segE - 1);
                const int s = snd_csr[c2];
                ssL[tid] = L0 ? specie[s] : s;
                rsL[tid] = rcv_csr[c2];
            }
        }
        // ---------- phase 1: MFMA 16 edges x 512; fp32 -> LDS ----------
        {
            const int pos = base + lo;
            const int cp = (pos < segE) ? pos : (segE - 1);
            const int eid = eidx[cp];
            const unsigned short* hrow = Hb + (size_t)eid * 64;
            const short8v a0 = *(const short8v*)(hrow + hi * 8);
            const short8v a1 = *(const short8v*)(hrow + 32 + hi * 8);
            f32x4 c16[8];
#pragma unroll
            for (int i = 0; i < 8; i++) c16[i] = (f32x4)(0.f);
#pragma unroll
            for (int tt = 0; tt < 8; tt++) {
                const int ct = wave * 8 + tt;
                const short8v b0 = *(const short8v*)(w2fl + ct * 1024 + lane * 8);
                const short8v b1 = *(const short8v*)(w2fl + ct * 1024 + 512 + lane * 8);
                c16[tt] = __builtin_amdgcn_mfma_f32_16x16x32_bf16(a0, b0, c16[tt], 0, 0, 0);
                c16[tt] = __builtin_amdgcn_mfma_f32_16x16x32_bf16(a1, b1, c16[tt], 0, 0, 0);
            }
            const int lc = lo & 7;
#pragma unroll
            for (int tt = 0; tt < 8; tt++) {
                const int ct = wave * 8 + tt;
                const int f = ct * 2 + (lo >> 3);
#pragma unroll
                for (int r = 0; r < 4; r++) {
                    const int el = hi * 4 + r;
                    R_lds[el * 532 + lc * 66 + f] = c16[tt][r];
                }
            }
        }
        __syncthreads();
        // ---------- phase 2: weight + segment reduce, DEPTH-2 prefetch ----------
        {
            // register sets: A = even k, B = odd k
            float sA0 = 0.f, sAf[4] = {0.f, 0.f, 0.f, 0.f};
            float sB0 = 0.f, sBf[4] = {0.f, 0.f, 0.f, 0.f};
            const int last = tcnt - 1;
            // prime k=0 -> A, k=1 -> B (clamped)
            if (L0) {
                sA0 = w_embed[ssL[0] * 64 + lane];
                sB0 = w_embed[ssL[(1 < tcnt) ? 1 : last] * 64 + lane];
            } else {
                const unsigned short* fa = featsB + (size_t)ssL[0] * 1024;
                sA0 = bf16tof(fa[lane]);
#pragma unroll
                for (int j = 0; j < 4; j++) sAf[j] = bf16tof(fa[(mbase + j) * 64 + lane]);
                const unsigned short* fb = featsB + (size_t)ssL[(1 < tcnt) ? 1 : last] * 1024;
                sB0 = bf16tof(fb[lane]);
#pragma unroll
                for (int j = 0; j < 4; j++) sBf[j] = bf16tof(fb[(mbase + j) * 64 + lane]);
            }
            for (int k = 0; k < tcnt; k += 2) {
                // ---- even k: prefetch k+2 -> A', compute with A ----
                float tA0 = 0.f, tAf[4] = {0.f, 0.f, 0.f, 0.f};
                {
                    const int kp = (k + 2 <= last) ? k + 2 : last;
                    if (L0) {
                        tA0 = w_embed[ssL[kp] * 64 + lane];
                    } else {
                        const unsigned short* f_ = featsB + (size_t)ssL[kp] * 1024;
                        tA0 = bf16tof(f_[lane]);
#pragma unroll
                        for (int j = 0; j < 4; j++) tAf[j] = bf16tof(f_[(mbase + j) * 64 + lane]);
                    }
                }
                {
                    const int node = rsL[k];
                    if (node != cur) {
                        if (cur >= 0) {
#pragma unroll
                            for (int j = 0; j < 4; j++)
                                agg[(size_t)cur * 1024 + (mbase + j) * 64 + lane] = acc[j] * 0.25f;
                        }
#pragma unroll
                        for (int j = 0; j < 4; j++) acc[j] = 0.f;
                        cur = node;
                    }
                    const float* Rt = R_lds + k * 532;
#pragma unroll
                    for (int j = 0; j < 4; j++) {
                        const int m = mbase + j;
                        const int l = l_of_m(m);
                        const float r0 = Rt[(2 * l) * 66 + lane];
                        const float r1 = Rt[(2 * l + 1) * 66 + lane];
                        const float ym = ysL[k][m];
                        const float fsm = L0 ? ((m == 0) ? sA0 : 0.f) : sAf[j];
                        acc[j] += r0 * sA0 * ym + r1 * fsm;
                    }
                }
                // ---- odd k+1: prefetch k+3 -> B', compute with B ----
                if (k + 1 < tcnt) {
                    float tB0 = 0.f, tBf[4] = {0.f, 0.f, 0.f, 0.f};
                    {
                        const int kp = (k + 3 <= last) ? k + 3 : last;
                        if (L0) {
                            tB0 = w_embed[ssL[kp] * 64 + lane];
                        } else {
                            const unsigned short* f_ = featsB + (size_t)ssL[kp] * 1024;
                            tB0 = bf16tof(f_[lane]);
#pragma unroll
                            for (int j = 0; j < 4; j++) tBf[j] = bf16tof(f_[(mbase + j) * 64 + lane]);
                        }
                    }
                    {
                        const int kk = k + 1;
                        const int node = rsL[kk];
                        if (node != cur) {
                            if (cur >= 0) {
#pragma unroll
                                for (int j = 0; j < 4; j++)
                                    agg[(size_t)cur * 1024 + (mbase + j) * 64 + lane] = acc[j] * 0.25f;
                            }
#pragma unroll
                            for (int j = 0; j < 4; j++) acc[j] = 0.f;
                            cur = node;
                        }
                        const float* Rt = R_lds + kk * 532;
#pragma unroll
                        for (int j = 0; j < 4; j++) {
                            const int m = mbase + j;
                            const int l = l_of_m(m);
                            const float r0 = Rt[(2 * l) * 66 + lane];
                            const float r1 = Rt[(2 * l + 1) * 66 + lane];
                            const float ym = ysL[kk][m];
                            const float fsm = L0 ? ((m == 0) ? sB0 : 0.f) : sBf[j];
                            acc[j] += r0 * sB0 * ym + r1 * fsm;
                        }
                    }
                    sB0 = tB0;
#pragma unroll
                    for (int j = 0; j < 4; j++) sBf[j] = tBf[j];
                }
                sA0 = tA0;
#pragma unroll
                for (int j = 0; j < 4; j++) sAf[j] = tAf[j];
            }
        }
        __syncthreads();
    }
    if (cur >= 0) {
#pragma unroll
        for (int j = 0; j < 4; j++)
            agg[(size_t)cur * 1024 + (mbase + j) * 64 + lane] = acc[j] * 0.25f;
    }
    // zero-degree nodes (agg never memset)
#pragma unroll
    for (int d = 0; d < 2; d++) {
        const int nn = n0 + d;
        if (nn < N && offs[nn] == offs[nn + 1]) {
#pragma unroll
            for (int j = 0; j < 4; j++)
                agg[(size_t)nn * 1024 + (mbase + j) * 64 + lane] = 0.f;
        }
    }
}

// ========== K2: node0 (readlane-VALU matvec)  |  geo+H(L1) tail blocks ==========
__global__ void k2_kernel(const float* __restrict__ agg,
                          const int* __restrict__ specie,
                          const float* __restrict__ w_skip0,
                          const float* __restrict__ w_poly0,
                          const float* __restrict__ w_read0,
                          unsigned short* __restrict__ featsB,
                          float* __restrict__ featsF,
                          int useBF16,
                          float* __restrict__ out, int N,
                          const float* __restrict__ vectors,
                          const float* __restrict__ w1L1,
                          unsigned short* __restrict__ Hb, int E) {
    if (blockIdx.x >= N) {
        const int e = (blockIdx.x - N) * 256 + threadIdx.x;
        if (e >= E) return;
        float ye[16], remb[NRAD];
        geo_core(vectors, e, ye, remb);
        hid_write(remb, w1L1, Hb, e);
        return;
    }
    const int n = blockIdx.x;
    const int g = threadIdx.x & 63;
    const int mb = threadIdx.x >> 6;
    const int sp = specie[n];
    const float* W = w_skip0 + (size_t)sp * 4 * F * F;

    float areg[4];
#pragma unroll
    for (int j = 0; j < 4; j++) areg[j] = agg[(size_t)n * 1024 + (mb * 4 + j) * 64 + g];

    float h[4] = {0.f, 0.f, 0.f, 0.f};
    if (mb == 0) {            // m0 -> l0 ; m1..3 -> l1
        const float* W0 = W;
        const float* W1 = W + 4096;
#pragma unroll
        for (int f = 0; f < 64; f++) {
            const float w0 = W0[f * 64 + g];
            const float w1 = W1[f * 64 + g];
            h[0] += lanebcast(areg[0], f) * w0;
            h[1] += lanebcast(areg[1], f) * w1;
            h[2] += lanebcast(areg[2], f) * w1;
            h[3] += lanebcast(areg[3], f) * w1;
        }
    } else if (mb == 1) {     // m4..7 -> l2
        const float* W2 = W + 8192;
#pragma unroll
        for (int f = 0; f < 64; f++) {
            const float w2 = W2[f * 64 + g];
            h[0] += lanebcast(areg[0], f) * w2;
            h[1] += lanebcast(areg[1], f) * w2;
            h[2] += lanebcast(areg[2], f) * w2;
            h[3] += lanebcast(areg[3], f) * w2;
        }
    } else if (mb == 2) {     // m8 -> l2 ; m9..11 -> l3
        const float* W2 = W + 8192;
        const float* W3 = W + 12288;
#pragma unroll
        for (int f = 0; f < 64; f++) {
            const float w2 = W2[f * 64 + g];
            const float w3 = W3[f * 64 + g];
            h[0] += lanebcast(areg[0], f) * w2;
            h[1] += lanebcast(areg[1], f) * w3;
            h[2] += lanebcast(areg[2], f) * w3;
            h[3] += lanebcast(areg[3], f) * w3;
        }
    } else {                  // m12..15 -> l3
        const float* W3 = W + 12288;
#pragma unroll
        for (int f = 0; f < 64; f++) {
            const float w3 = W3[f * 64 + g];
            h[0] += lanebcast(areg[0], f) * w3;
            h[1] += lanebcast(areg[1], f) * w3;
            h[2] += lanebcast(areg[2], f) * w3;
            h[3] += lanebcast(areg[3], f) * w3;
        }
    }

    __shared__ float h0L[64];
    if (mb == 0) h0L[g] = h[0];
    __syncthreads();
    const float s = h0L[g];
    const float c0 = w_poly0[(0 * NSPEC + sp) * F + g];
    const float c1 = w_poly0[(1 * NSPEC + sp) * F + g];
    const float c2 = w_poly0[(2 * NSPEC + sp) * F + g];
    const float scale = c0 + c1 * s + c2 * s * s;
    float f0val = 0.0f;
#pragma unroll
    for (int j = 0; j < 4; j++) {
        const int m = mb * 4 + j;
        const float fv = h[j] * scale;
        const size_t idx = (size_t)n * 1024 + m * 64 + g;
        if (useBF16) featsB[idx] = bf16bits(fv);
        else         featsF[idx] = fv;
        if (m == 0) f0val = fv;
    }
    if (mb == 0) {
        float v = f0val * w_read0[g];
#pragma unroll
        for (int off = 32; off > 0; off >>= 1) v += __shfl_down(v, off);
        if (g == 0) out[(size_t)n * 2 + 0] = v;
    }
}

// ---------- node kernel, layer 1 (bf16 feats, readlane-VALU broadcasts) ----------
__global__ void node1_kernel(const float* __restrict__ agg,
                             const unsigned short* __restrict__ featsB,
                             const int* __restrict__ specie,
                             const float* __restrict__ w_skip1,
                             const float* __restrict__ w_poly1,
                             const float* __restrict__ w_mlp1,
                             const float* __restrict__ w_mlp2,
                             float* __restrict__ out, int N) {
    const int wave = threadIdx.x >> 6;
    const int lane = threadIdx.x & 63;
    const int n = blockIdx.x * 4 + wave;
    const int sp = specie[n];
    const float* W0 = w_skip1 + (size_t)sp * 4 * F * F;
    const float fv = bf16tof(featsB[(size_t)n * 1024 + lane]);
    float sc0 = 0.0f;
#pragma unroll
    for (int f = 0; f < F; f++) {
        sc0 += lanebcast(fv, f) * W0[f * F + lane];
    }
    const float h0 = agg[(size_t)n * 1024 + lane];
    const float c0 = w_poly1[(0 * NSPEC + sp) * F + lane];
    const float c1 = w_poly1[(1 * NSPEC + sp) * F + lane];
    const float c2 = w_poly1[(2 * NSPEC + sp) * F + lane];
    const float scale = c0 + c1 * h0 + c2 * h0 * h0;
    const float f2 = h0 * scale + sc0;
    float acc = 0.0f;
#pragma unroll
    for (int gg = 0; gg < F; gg++) {
        const float fg = lanebcast(f2, gg);
        if (lane < HID_READ) acc += fg * w_mlp1[gg * HID_READ + lane];
    }
    float o = 0.0f;
    if (lane < HID_READ) o = silu(acc) * w_mlp2[lane];
#pragma unroll
    for (int off = 32; off > 0; off >>= 1) o += __shfl_down(o, off);
    if (lane == 0) out[(size_t)n * 2 + 1] = o;
}

// ---------- fallback node1 (fp32 feats) ----------
__global__ void node1f_kernel(const float* __restrict__ agg,
                              const float* __restrict__ feats,
                              const int* __restrict__ specie,
                              const float* __restrict__ w_skip1,
                              const float* __restrict__ w_poly1,
                              const float* __restrict__ w_mlp1,
                              const float* __restrict__ w_mlp2,
                              float* __restrict__ out, int N) {
    const int wave = threadIdx.x >> 6;
    const int lane = threadIdx.x & 63;
    const int n = blockIdx.x * 4 + wave;
    const int sp = specie[n];
    const float* W0 = w_skip1 + (size_t)sp * 4 * F * F;
    const float fv = feats[(size_t)n * 1024 + lane];
    float sc0 = 0.0f;
#pragma unroll 8
    for (int f = 0; f < F; f++) {
        const float ff = __shfl(fv, f);
        sc0 += ff * W0[f * F + lane];
    }
    const float h0 = agg[(size_t)n * 1024 + lane];
    const float c0 = w_poly1[(0 * NSPEC + sp) * F + lane];
    const float c1 = w_poly1[(1 * NSPEC + sp) * F + lane];
    const float c2 = w_poly1[(2 * NSPEC + sp) * F + lane];
    const float scale = c0 + c1 * h0 + c2 * h0 * h0;
    const float f2 = h0 * scale + sc0;
    float acc = 0.0f;
#pragma unroll 8
    for (int gg = 0; gg < F; gg++) {
        const float fg = __shfl(f2, gg);
        if (lane < HID_READ) acc += fg * w_mlp1[gg * HID_READ + lane];
    }
    float o = 0.0f;
    if (lane < HID_READ) o = silu(acc) * w_mlp2[lane];
#pragma unroll
    for (int off = 32; off > 0; off >>= 1) o += __shfl_down(o, off);
    if (lane == 0) out[(size_t)n * 2 + 1] = o;
}

// ---------- fallback (round-1, known-passing) edge kernel ----------
__global__ void edge_kernel(const float* __restrict__ Y, const float* __restrict__ Remb,
                            const float* __restrict__ feats_t,
                            const int* __restrict__ senders, const int* __restrict__ receivers,
                            const float* __restrict__ w1, const float* __restrict__ w2,
                            float* __restrict__ agg_t, int E) {
    const int wave = threadIdx.x >> 6;
    const int lane = threadIdx.x & 63;
    const int e = blockIdx.x * 4 + wave;
    __shared__ float hbuf[4][64];
    const float* remb = Remb + (size_t)e * NRAD;
    float acc = 0.0f;
#pragma unroll
    for (int k = 0; k < NRAD; k++) acc += remb[k] * w1[k * F + lane];
    hbuf[wave][lane] = silu(acc);
    __syncthreads();
    float r8[8] = {0.f, 0.f, 0.f, 0.f, 0.f, 0.f, 0.f, 0.f};
    const float* w2base = w2 + lane * 8;
#pragma unroll 8
    for (int j = 0; j < HID_R; j++) {
        float hj = hbuf[wave][j];
        const float4 a = *(const float4*)(w2base + j * 512);
        const float4 b = *(const float4*)(w2base + j * 512 + 4);
        r8[0] += hj * a.x; r8[1] += hj * a.y; r8[2] += hj * a.z; r8[3] += hj * a.w;
        r8[4] += hj * b.x; r8[5] += hj * b.y; r8[6] += hj * b.z; r8[7] += hj * b.w;
    }
    const int snd = senders[e];
    const int rcv = receivers[e];
    const float* fsrc = feats_t + (size_t)snd * (F * LDIM);
    float* adst = agg_t + (size_t)rcv * (F * LDIM);
    const float s0 = fsrc[lane];
    const float* Ye = Y + (size_t)e * 16;
#pragma unroll
    for (int m = 0; m < LDIM; m++) {
        const int l = l_of_m(m);
        const float ym = Ye[m];
        const float fsm = fsrc[m * F + lane];
        const float val = r8[l * 2 + 0] * s0 * ym + r8[l * 2 + 1] * fsm;
        atomicAdd(adst + m * F + lane, val * 0.25f);
    }
}

static inline size_t alignup(size_t x) { return (x + 255) & ~(size_t)255; }

extern "C" void kernel_launch(void* const* d_in, const int* in_sizes, int n_in,
                              void* d_out, int out_size, void* d_ws, size_t ws_size,
                              hipStream_t stream) {
    const float* vectors   = (const float*)d_in[0];
    const int*   specie    = (const int*)d_in[1];
    const int*   senders   = (const int*)d_in[2];
    const int*   receivers = (const int*)d_in[3];
    const float* w_embed   = (const float*)d_in[4];
    const float* w_r1      = (const float*)d_in[5];
    const float* w_r2      = (const float*)d_in[6];
    const float* w_skip    = (const float*)d_in[7];
    const float* w_poly    = (const float*)d_in[8];
    const float* w_read0   = (const float*)d_in[9];
    const float* w_mlp1    = (const float*)d_in[10];
    const float* w_mlp2    = (const float*)d_in[11];
    float* out = (float*)d_out;

    const int E = in_sizes[0] / 3;   // 160000
    const int N = in_sizes[1];       // 10000
    const int ngeo = (E + 255) / 256;

    // ---- fast-path workspace layout (~95 MB) ----
    char* base = (char*)d_ws;
    size_t off = 0;
    float* Y      = (float*)(base + off); off += alignup((size_t)E * 16 * sizeof(float));
    unsigned short* featsB = (unsigned short*)(base + off); off += alignup((size_t)N * F * LDIM * sizeof(unsigned short));
    float* agg    = (float*)(base + off); off += alignup((size_t)N * F * LDIM * sizeof(float));
    unsigned short* Hb = (unsigned short*)(base + off); off += alignup((size_t)E * 64 * sizeof(unsigned short));
    int* cnt      = (int*)(base + off);   off += alignup((size_t)N * sizeof(int));
    int* cur      = (int*)(base + off);   off += alignup((size_t)N * sizeof(int));
    int* offs     = (int*)(base + off);   off += alignup((size_t)(N + 1) * sizeof(int));
    int* eidx     = (int*)(base + off);   off += alignup((size_t)E * sizeof(int));
    int* snd_csr  = (int*)(base + off);   off += alignup((size_t)E * sizeof(int));
    int* rcv_csr  = (int*)(base + off);   off += alignup((size_t)E * sizeof(int));
    unsigned short* w2f = (unsigned short*)(base + off); off += alignup((size_t)2 * 32768 * sizeof(unsigned short));
    const size_t need = off;

    const size_t aggBytes = (size_t)N * F * LDIM * sizeof(float);

    if (ws_size >= need) {
        // =========== fast path ===========
        hipMemsetAsync(cnt, 0, (size_t)N * sizeof(int), stream);
        hipMemsetAsync(cur, 0, (size_t)N * sizeof(int), stream);
        k1_kernel<<<ngeo + 2, 256, 0, stream>>>(vectors, w_r1, w_r2, receivers,
                                                Y, Hb, cnt, w2f, E, ngeo);
        scan_kernel<<<1, 1024, 0, stream>>>(cnt, offs, N);
        scatter_kernel<<<ngeo, 256, 0, stream>>>(receivers, senders, offs, cur,
                                                 eidx, snd_csr, rcv_csr, E);
        // ---- layer 0 ----
        fused_edge_kernel<true><<<N / 2, 256, 0, stream>>>(
            Hb, w2f, Y, nullptr, w_embed, specie, offs, eidx, snd_csr, rcv_csr, agg, N);
        // ---- node0 (writes bf16 feats) + geo/H for layer 1 ----
        k2_kernel<<<N + ngeo, 256, 0, stream>>>(agg, specie,
                                                w_skip + (size_t)0 * NSPEC * 4 * F * F,
                                                w_poly + (size_t)0 * 3 * NSPEC * F,
                                                w_read0, featsB, nullptr, 1, out, N,
                                                vectors, w_r1 + NRAD * HID_R, Hb, E);
        // ---- layer 1 ----
        fused_edge_kernel<false><<<N / 2, 256, 0, stream>>>(
            Hb, w2f + 32768, Y, featsB, w_embed, specie, offs, eidx, snd_csr, rcv_csr, agg, N);
        node1_kernel<<<N / 4, 256, 0, stream>>>(agg, featsB, specie,
                                                w_skip + (size_t)1 * NSPEC * 4 * F * F,
                                                w_poly + (size_t)1 * 3 * NSPEC * F,
                                                w_mlp1, w_mlp2, out, N);
    } else {
        // =========== fallback: round-1 atomic path (fp32 throughout) ===========
        size_t fo = 0;
        float* Yf    = (float*)(base + fo); fo += alignup((size_t)E * 16 * sizeof(float));
        float* Remb  = (float*)(base + fo); fo += alignup((size_t)E * NRAD * sizeof(float));
        float* featsF= (float*)(base + fo); fo += alignup((size_t)N * F * LDIM * sizeof(float));
        float* aggF  = (float*)(base + fo);

        geo_kernel<<<ngeo, 256, 0, stream>>>(vectors, Yf, Remb, E);
        init_feats_kernel<<<N, 256, 0, stream>>>(w_embed, specie, featsF, N);
        hipMemsetAsync(aggF, 0, aggBytes, stream);
        edge_kernel<<<E / 4, 256, 0, stream>>>(Yf, Remb, featsF, senders, receivers,
                                               w_r1, w_r2, aggF, E);
        k2_kernel<<<N, 256, 0, stream>>>(aggF, specie,
                                         w_skip + (size_t)0 * NSPEC * 4 * F * F,
                                         w_poly + (size_t)0 * 3 * NSPEC * F,
                                         w_read0, nullptr, featsF, 0, out, N,
                                         vectors, w_r1 + NRAD * HID_R, nullptr, 0);
        hipMemsetAsync(aggF, 0, aggBytes, stream);
        edge_kernel<<<E / 4, 256, 0, stream>>>(Yf, Remb, featsF, senders, receivers,
                                               w_r1 + NRAD * HID_R, w_r2 + HID_R * 512,
                                               aggF, E);
        node1f_kernel<<<N / 4, 256, 0, stream>>>(aggF, featsF, specie,
                                                 w_skip + (size_t)1 * NSPEC * 4 * F * F,
                                                 w_poly + (size_t)1 * 3 * NSPEC * F,
                                                 w_mlp1, w_mlp2, out, N);
    }
}